// Round 12
// baseline (475.913 us; speedup 1.0000x reference)
//
#include <hip/hip_runtime.h>

// Problem constants (fixed by the reference)
#define D_   8
#define Q_   1024
#define DB_  32768
#define F_   64
#define NB_  128      // num_buckets = num_neighbors
#define BS_  256      // bucket_size = DB/NB
#define NT_  (Q_*D_*NB_)   // 1,048,576 (q,d,j) triples
#define SPLIT_ 8      // split of the b-range across blocks
#define MARGIN_  6e-4f  // scan top-2 gap below which fixA re-ranks exactly
#define MARGIN2_ 2e-4   // fixA exact gap below which fixB does fp64 softmax
#define FLAG_CAP_ 262144

typedef __attribute__((ext_vector_type(16))) float    f32x16;
typedef __attribute__((ext_vector_type(4)))  float    f32x4;
typedef __attribute__((ext_vector_type(8)))  short    short8;
typedef __attribute__((ext_vector_type(8)))  __bf16   bf16x8;

static __device__ __forceinline__ f32x16 mfma32(short8 a, short8 b, f32x16 c) {
    return __builtin_amdgcn_mfma_f32_32x32x16_bf16(
        __builtin_bit_cast(bf16x8, a), __builtin_bit_cast(bf16x8, b), c, 0, 0, 0);
}

// ---------------------------------------------------------------------------
// In-register RNE split: x = hi + lo (both bf16, native casts ->
// v_cvt_pk_bf16_f32; verified on-device R9/R10/R11).
// ---------------------------------------------------------------------------
static __device__ __forceinline__ void cvt8f(float4 a, float4 b,
                                             short8& kh, short8& kl) {
    float x0 = a.x, x1 = a.y, x2 = a.z, x3 = a.w;
    float x4 = b.x, x5 = b.y, x6 = b.z, x7 = b.w;
    bf16x8 h, l;
    h[0] = (__bf16)x0; l[0] = (__bf16)(x0 - (float)h[0]);
    h[1] = (__bf16)x1; l[1] = (__bf16)(x1 - (float)h[1]);
    h[2] = (__bf16)x2; l[2] = (__bf16)(x2 - (float)h[2]);
    h[3] = (__bf16)x3; l[3] = (__bf16)(x3 - (float)h[3]);
    h[4] = (__bf16)x4; l[4] = (__bf16)(x4 - (float)h[4]);
    h[5] = (__bf16)x5; l[5] = (__bf16)(x5 - (float)h[5]);
    h[6] = (__bf16)x6; l[6] = (__bf16)(x6 - (float)h[6]);
    h[7] = (__bf16)x7; l[7] = (__bf16)(x7 - (float)h[7]);
    kh = __builtin_bit_cast(short8, h);
    kl = __builtin_bit_cast(short8, l);
}

// ---------------------------------------------------------------------------
// K1: bf16 3-pass MFMA scan, R11 geometry (64q x 64j, 4 waves, 36KB LDS,
// 4 blocks/CU). NEW: TWO accumulators c0/c1 (6-MFMA dependency chain each,
// interleaved) instead of one 12-deep C-chain — dependent-MFMA latency >>
// 8-cyc throughput, so the single chain serialized each block-step.
// Final score v = c0[r] + c1[r] (same sum, different order: fp32-level
// reorder noise << margin). Everything else identical to R11.
// ---------------------------------------------------------------------------
__global__ __launch_bounds__(256, 4) void k_scan_mfma(
    const float* __restrict__ key_db, const float* __restrict__ query,
    float* __restrict__ m1p, float* __restrict__ m2p)
{
    __shared__ short kbuf[2][2][64][72];    // [buf][part][row][col] = 36 KB
    const int tid  = threadIdx.x;
    const int d    = blockIdx.x & 7;        // dataset pinned to XCD
    const int idx  = blockIdx.x >> 3;       // 0..255 per d
    const int qi   = idx & 15;
    const int ji   = (idx >> 4) & 1;
    const int half = idx >> 5;              // 0..7
    const int q0 = qi * 64, j0 = ji * 64;
    const int wv = tid >> 6, lane = tid & 63;
    const int qg = wv >> 1, jg = wv & 1;
    const int lrow = lane & 31, kg = lane >> 5;

    short8 qh[4], ql[4];
    {
        const float* qr = query + ((size_t)(q0 + qg * 32 + lrow) * D_ + d) * F_ + kg * 8;
#pragma unroll
        for (int ks = 0; ks < 4; ++ks) {
            float4 A = *(const float4*)(qr + ks * 16);
            float4 B = *(const float4*)(qr + ks * 16 + 4);
            cvt8f(A, B, qh[ks], ql[ks]);
        }
    }

    float m1q[16], m2[16];
#pragma unroll
    for (int r = 0; r < 16; ++r) { m1q[r] = -3e38f; m2[r] = -3e38f; }

    const int nsteps = BS_ / SPLIT_;       // 32 b-steps per block
    const int bstart = half * nsteps;
    const int r0 = tid >> 2, sub16 = (tid & 3) * 16;
    const float* sp = key_db + (size_t)d * DB_ * F_
                    + ((size_t)bstart * NB_ + j0) * F_
                    + (size_t)r0 * F_ + sub16;
    const size_t kstep = (size_t)NB_ * F_;

    { // prologue: stage step 0 into buf 0
        float4 A0 = *(const float4*)(sp);
        float4 A1 = *(const float4*)(sp + 4);
        float4 B0 = *(const float4*)(sp + 8);
        float4 B1 = *(const float4*)(sp + 12);
        short8 h0, l0, h1, l1;
        cvt8f(A0, A1, h0, l0);
        cvt8f(B0, B1, h1, l1);
        *(short8*)&kbuf[0][0][r0][sub16]     = h0;
        *(short8*)&kbuf[0][0][r0][sub16 + 8] = h1;
        *(short8*)&kbuf[0][1][r0][sub16]     = l0;
        *(short8*)&kbuf[0][1][r0][sub16 + 8] = l1;
    }

    const int jrow = jg * 32 + lrow;
    int cur = 0;
    for (int p = 0; p < nsteps; ++p) {
        __syncthreads();
        float4 A0, A1, B0, B1;
        if (p + 1 < nsteps) {
            const float* np = sp + (size_t)(p + 1) * kstep;
            A0 = *(const float4*)(np);
            A1 = *(const float4*)(np + 4);
            B0 = *(const float4*)(np + 8);
            B1 = *(const float4*)(np + 12);
        }

        f32x16 c0 = {0,0,0,0,0,0,0,0,0,0,0,0,0,0,0,0};
        f32x16 c1 = {0,0,0,0,0,0,0,0,0,0,0,0,0,0,0,0};
#pragma unroll
        for (int ks = 0; ks < 4; ++ks) {   // hi fragment feeds BOTH chains
            short8 kf = *(const short8*)&kbuf[cur][0][jrow][ks * 16 + kg * 8];
            c0 = mfma32(qh[ks], kf, c0);
            c1 = mfma32(ql[ks], kf, c1);
        }
#pragma unroll
        for (int ks = 0; ks < 4; ++ks) {   // lo fragments alternate chains
            short8 kf = *(const short8*)&kbuf[cur][1][jrow][ks * 16 + kg * 8];
            if (ks & 1) c1 = mfma32(qh[ks], kf, c1);
            else        c0 = mfma32(qh[ks], kf, c0);
        }

        const unsigned bb = (unsigned)(bstart + p);
#pragma unroll
        for (int r = 0; r < 16; ++r) {     // packed branchless top-2
            float v = c0[r] + c1[r];
            float vq = __uint_as_float((__float_as_uint(v) & 0xFFFFFF00u) | bb);
            m2[r]  = __builtin_amdgcn_fmed3f(vq, m1q[r], m2[r]);
            m1q[r] = fmaxf(m1q[r], vq);
        }

        if (p + 1 < nsteps) {
            short8 h0, l0, h1, l1;
            cvt8f(A0, A1, h0, l0);
            cvt8f(B0, B1, h1, l1);
            const int nb = cur ^ 1;
            *(short8*)&kbuf[nb][0][r0][sub16]     = h0;
            *(short8*)&kbuf[nb][0][r0][sub16 + 8] = h1;
            *(short8*)&kbuf[nb][1][r0][sub16]     = l0;
            *(short8*)&kbuf[nb][1][r0][sub16 + 8] = l1;
            cur = nb;
        }
    }

#pragma unroll
    for (int r = 0; r < 16; ++r) {
        const int q = q0 + qg * 32 + 4 * kg + (r & 3) + 8 * (r >> 2);
        const size_t t = (((size_t)q * D_ + d) << 7) + j0 + jrow;
        const size_t pp = (size_t)half * NT_ + t;
        m1p[pp] = m1q[r]; m2p[pp] = m2[r];
    }
}

// ---------------------------------------------------------------------------
// Merge split-b partials -> final argmax byte + near-tie flag list.
// ---------------------------------------------------------------------------
__global__ void k_merge(const float* __restrict__ m1p, const float* __restrict__ m2p,
                        unsigned char* __restrict__ idx0b,
                        int* __restrict__ flag_cnt, int* __restrict__ flag_list)
{
    int t = blockIdx.x * 256 + threadIdx.x;
    if (t >= NT_) return;
    float m1 = -3e38f, m2 = -3e38f;
#pragma unroll
    for (int h = 0; h < SPLIT_; ++h) {
        float a    = m1p[(size_t)h * NT_ + t];
        float bsec = m2p[(size_t)h * NT_ + t];
        if (a > m1) { m2 = m1; m1 = a; }
        else if (a > m2) m2 = a;
        if (bsec > m2) m2 = bsec;
    }
    idx0b[t] = (unsigned char)(__float_as_uint(m1) & 0xFFu);
    if (m2 >= m1 - MARGIN_) {
        int pos = atomicAdd(flag_cnt, 1);
        if (pos < FLAG_CAP_) flag_list[pos] = t;
    }
}

// ---------------------------------------------------------------------------
// FixA: exact fp64-accum re-rank of flagged triples.
// ---------------------------------------------------------------------------
__global__ void k_fixA(const float* __restrict__ query, const float* __restrict__ key_db,
                       const int* __restrict__ flag_cnt, const int* __restrict__ flag_list,
                       unsigned char* __restrict__ idx0b, int* __restrict__ flag2_cnt,
                       int* __restrict__ flag2_list)
{
    int cnt = *flag_cnt;
    if (cnt > FLAG_CAP_) cnt = FLAG_CAP_;
    int gw   = (blockIdx.x * blockDim.x + threadIdx.x) >> 6;
    int lane = threadIdx.x & 63;
    int nw   = (gridDim.x * blockDim.x) >> 6;

    for (int w = gw; w < cnt; w += nw) {
        int t = flag_list[w];
        int j = t & 127, d = (t >> 7) & 7, qi = t >> 10;
        const float* qrow = query + ((size_t)qi * D_ + d) * F_;
        const float* kb = key_db + (size_t)d * DB_ * F_;

        double m1 = -1e300, m2 = -1e300; int i1 = 0;
#pragma unroll
        for (int i = 0; i < 4; ++i) {
            int b = lane * 4 + i;
            const float* krow = kb + ((size_t)b * NB_ + j) * F_;
            double a = 0.0;
            for (int k2 = 0; k2 < F_; ++k2) a += (double)qrow[k2] * (double)krow[k2];
            if (a > m1) { m2 = m1; m1 = a; i1 = b; }
            else if (a > m2) m2 = a;
        }
        for (int off = 32; off; off >>= 1) {
            double om1 = __shfl_xor(m1, off);
            double om2 = __shfl_xor(m2, off);
            int    oi  = __shfl_xor(i1, off);
            if (om1 > m1) { m2 = fmax(m1, om2); m1 = om1; i1 = oi; }
            else          { m2 = fmax(m2, om1); }
        }
        if (lane == 0) {
            idx0b[t] = (unsigned char)i1;
            if (m1 - m2 < MARGIN2_) {
                int pos = atomicAdd(flag2_cnt, 1);
                if (pos < 4096) flag2_list[pos] = t;
            }
        }
    }
}

// ---------------------------------------------------------------------------
// K2: gather (R10/R11 pair form). Non-temporal stores.
// ---------------------------------------------------------------------------
__global__ void k_gather(const float* __restrict__ key_db, const float* __restrict__ value_db,
                         const unsigned char* __restrict__ idx0b, f32x4* __restrict__ out)
{
    const int total = NT_ * 16;   // key-half float4 count
    const int stride = gridDim.x * 256;
    int e = blockIdx.x * 256 + threadIdx.x;
#pragma unroll 2
    for (; e < total; e += stride) {
        int t  = e >> 4;
        int fc = e & 15;
        int j = t & 127;
        int d = (t >> 7) & 7;
        int b = idx0b[t];
        size_t rowoff = ((size_t)d * DB_ + b * NB_ + j) * F_ + fc * 4;
        f32x4 kv = *(const f32x4*)(key_db + rowoff);
        f32x4 vv = *(const f32x4*)(value_db + rowoff);
        __builtin_nontemporal_store(kv, &out[e]);
        __builtin_nontemporal_store(vv, &out[(size_t)NT_ * 16 + e]);
    }
}

// ---------------------------------------------------------------------------
// FixB: exact fp64 softmax for true near-tie triples.
// ---------------------------------------------------------------------------
__global__ void k_fixB(const float* __restrict__ query, const float* __restrict__ key_db,
                       const float* __restrict__ value_db, const int* __restrict__ flag_cnt,
                       const int* __restrict__ flag_list, float* __restrict__ out)
{
    int cnt = *flag_cnt;
    if (cnt > 4096) cnt = 4096;
    int gw   = (blockIdx.x * blockDim.x + threadIdx.x) >> 6;
    int lane = threadIdx.x & 63;
    int nw   = (gridDim.x * blockDim.x) >> 6;

    for (int w = gw; w < cnt; w += nw) {
        int t = flag_list[w];
        int j = t & 127, d = (t >> 7) & 7, qi = t >> 10;
        const float* qrow = query + ((size_t)qi * D_ + d) * F_;
        const float* kb = key_db + (size_t)d * DB_ * F_;
        const float* vb = value_db + (size_t)d * DB_ * F_;

        double sv[4];
#pragma unroll
        for (int i = 0; i < 4; ++i) {
            int b = lane * 4 + i;
            const float* krow = kb + ((size_t)b * NB_ + j) * F_;
            double a = 0.0;
            for (int k2 = 0; k2 < F_; ++k2) a += (double)qrow[k2] * (double)krow[k2];
            sv[i] = a;
        }
        double m = fmax(fmax(sv[0], sv[1]), fmax(sv[2], sv[3]));
        for (int off = 32; off; off >>= 1) m = fmax(m, __shfl_xor(m, off));
        double ev[4];
        double es = 0.0;
#pragma unroll
        for (int i = 0; i < 4; ++i) { ev[i] = exp((sv[i] - m) * 1e6); es += ev[i]; }
        for (int off = 32; off; off >>= 1) es += __shfl_xor(es, off);
        double inv = 1.0 / es;
#pragma unroll
        for (int i = 0; i < 4; ++i) ev[i] *= inv;

        double ak = 0.0, av = 0.0;
        for (int src = 0; src < 64; ++src) {
#pragma unroll
            for (int i = 0; i < 4; ++i) {
                double wv = __shfl(ev[i], src);
                if (wv > 1e-300) {
                    int b = src * 4 + i;
                    size_t o = ((size_t)b * NB_ + j) * F_ + lane;
                    ak += wv * (double)kb[o];
                    av += wv * (double)vb[o];
                }
            }
        }
        out[(size_t)t * F_ + lane] = (float)ak;
        out[(size_t)NT_ * F_ + (size_t)t * F_ + lane] = (float)av;
    }
}

// ---------------------------------------------------------------------------
extern "C" void kernel_launch(void* const* d_in, const int* in_sizes, int n_in,
                              void* d_out, int out_size, void* d_ws, size_t ws_size,
                              hipStream_t stream)
{
    const float* query    = (const float*)d_in[0];
    const float* key_db   = (const float*)d_in[1];
    const float* value_db = (const float*)d_in[2];
    float* out = (float*)d_out;

    unsigned char* idx0b = (unsigned char*)d_ws;
    int* flag_cnt   = (int*)((char*)d_ws + (size_t)NT_);
    int* flag2_cnt  = flag_cnt + 1;
    int* flag_list  = (int*)((char*)d_ws + (size_t)NT_ + 256);
    int* flag2_list = flag_list + FLAG_CAP_;

    float* m1p = (float*)d_out;                           // 32 MB
    float* m2p = m1p + (size_t)SPLIT_ * NT_;              // 32 MB

    (void)hipMemsetAsync(flag_cnt, 0, 8, stream);

    // INSTRUMENTATION: scan launched TWICE (idempotent — writes identical
    // partials). scan_time ~= total - 332.5us from R11. Deliberate temporary
    // regression to convert 4 rounds of estimates into a measurement.
    k_scan_mfma<<<2048, 256, 0, stream>>>(key_db, query, m1p, m2p);
    k_scan_mfma<<<2048, 256, 0, stream>>>(key_db, query, m1p, m2p);
    k_merge    <<<NT_ / 256, 256, 0, stream>>>(m1p, m2p, idx0b, flag_cnt, flag_list);
    k_fixA     <<<512,  256, 0, stream>>>(query, key_db, flag_cnt, flag_list,
                                          idx0b, flag2_cnt, flag2_list);
    k_gather   <<<4096, 256, 0, stream>>>(key_db, value_db, idx0b, (f32x4*)d_out);
    k_fixB     <<<256,  256, 0, stream>>>(query, key_db, value_db, flag2_cnt,
                                          flag2_list, out);
}

// Round 13
// 320.119 us; speedup vs baseline: 1.4867x; 1.4867x over previous
//
#include <hip/hip_runtime.h>

// Problem constants (fixed by the reference)
#define D_   8
#define Q_   1024
#define DB_  32768
#define F_   64
#define NB_  128      // num_buckets = num_neighbors
#define BS_  256      // bucket_size = DB/NB
#define NT_  (Q_*D_*NB_)   // 1,048,576 (q,d,j) triples
#define SPLIT_ 8      // split of the b-range across blocks
#define MARGIN_  6e-4f  // scan top-2 gap below which fixA re-ranks exactly
#define MARGIN2_ 2e-4   // fixA exact gap below which fixB does fp64 softmax
#define FLAG_CAP_ 262144

typedef __attribute__((ext_vector_type(16))) float    f32x16;
typedef __attribute__((ext_vector_type(4)))  float    f32x4;
typedef __attribute__((ext_vector_type(8)))  short    short8;
typedef __attribute__((ext_vector_type(8)))  __bf16   bf16x8;

static __device__ __forceinline__ f32x16 mfma32(short8 a, short8 b, f32x16 c) {
    return __builtin_amdgcn_mfma_f32_32x32x16_bf16(
        __builtin_bit_cast(bf16x8, a), __builtin_bit_cast(bf16x8, b), c, 0, 0, 0);
}

// ---------------------------------------------------------------------------
// In-register RNE split: x = hi + lo (both bf16, native casts ->
// v_cvt_pk_bf16_f32; verified on-device R9-R12).
// ---------------------------------------------------------------------------
static __device__ __forceinline__ void cvt8f(float4 a, float4 b,
                                             short8& kh, short8& kl) {
    float x0 = a.x, x1 = a.y, x2 = a.z, x3 = a.w;
    float x4 = b.x, x5 = b.y, x6 = b.z, x7 = b.w;
    bf16x8 h, l;
    h[0] = (__bf16)x0; l[0] = (__bf16)(x0 - (float)h[0]);
    h[1] = (__bf16)x1; l[1] = (__bf16)(x1 - (float)h[1]);
    h[2] = (__bf16)x2; l[2] = (__bf16)(x2 - (float)h[2]);
    h[3] = (__bf16)x3; l[3] = (__bf16)(x3 - (float)h[3]);
    h[4] = (__bf16)x4; l[4] = (__bf16)(x4 - (float)h[4]);
    h[5] = (__bf16)x5; l[5] = (__bf16)(x5 - (float)h[5]);
    h[6] = (__bf16)x6; l[6] = (__bf16)(x6 - (float)h[6]);
    h[7] = (__bf16)x7; l[7] = (__bf16)(x7 - (float)h[7]);
    kh = __builtin_bit_cast(short8, h);
    kl = __builtin_bit_cast(short8, l);
}

// ---------------------------------------------------------------------------
// K1: bf16 3-pass MFMA scan. Geometry: block = 128q x 64j, 8 waves
// (4qg x 2jg), 36KB double-buffered LDS, 2 blocks/CU (16 waves/CU — same
// occupancy as R11/R12, VGPR-capped either way) but staging bytes, cvt
// VALU, and barriers PER OUTPUT are HALVED vs the 64q block (measured
// scan = 143us at R12; staging/cvt was the dominant non-MFMA cost).
// d = XCD id; resident slab set per XCD = 4 halves x 1MB = L2-sized.
// Two accumulators (6-MFMA chains); top-2 with b packed into m1 low bits.
// ---------------------------------------------------------------------------
__global__ __launch_bounds__(512, 4) void k_scan_mfma(
    const float* __restrict__ key_db, const float* __restrict__ query,
    float* __restrict__ m1p, float* __restrict__ m2p)
{
    __shared__ short kbuf[2][2][64][72];    // [buf][part][row][col] = 36 KB
    const int tid  = threadIdx.x;
    const int d    = blockIdx.x & 7;        // dataset pinned to XCD
    const int idx  = blockIdx.x >> 3;       // 0..127 per d
    const int qi   = idx & 7;
    const int ji   = (idx >> 3) & 1;
    const int half = idx >> 4;              // 0..7
    const int q0 = qi * 128, j0 = ji * 64;
    const int wv = tid >> 6, lane = tid & 63;
    const int qg = wv >> 1, jg = wv & 1;
    const int lrow = lane & 31, kg = lane >> 5;

    short8 qh[4], ql[4];
    {
        const float* qr = query + ((size_t)(q0 + qg * 32 + lrow) * D_ + d) * F_ + kg * 8;
#pragma unroll
        for (int ks = 0; ks < 4; ++ks) {
            float4 A = *(const float4*)(qr + ks * 16);
            float4 B = *(const float4*)(qr + ks * 16 + 4);
            cvt8f(A, B, qh[ks], ql[ks]);
        }
    }

    float m1q[16], m2[16];
#pragma unroll
    for (int r = 0; r < 16; ++r) { m1q[r] = -3e38f; m2[r] = -3e38f; }

    const int nsteps = BS_ / SPLIT_;       // 32 b-steps per block
    const int bstart = half * nsteps;
    // staging: 512 thr x 32B = 16KB/step; thread covers row r0, 8 floats
    const int r0 = tid >> 3, sub8 = (tid & 7) * 8;
    const float* sp = key_db + (size_t)d * DB_ * F_
                    + ((size_t)bstart * NB_ + j0) * F_
                    + (size_t)r0 * F_ + sub8;
    const size_t kstep = (size_t)NB_ * F_;

    { // prologue: stage step 0 into buf 0
        float4 A0 = *(const float4*)(sp);
        float4 A1 = *(const float4*)(sp + 4);
        short8 h0, l0;
        cvt8f(A0, A1, h0, l0);
        *(short8*)&kbuf[0][0][r0][sub8] = h0;
        *(short8*)&kbuf[0][1][r0][sub8] = l0;
    }

    const int jrow = jg * 32 + lrow;       // j index 0..63 within block
    int cur = 0;
    for (int p = 0; p < nsteps; ++p) {
        __syncthreads();                   // buf[cur] ready; buf[cur^1] free
        float4 A0, A1;
        if (p + 1 < nsteps) {              // issue next-step fp32 loads early
            const float* np = sp + (size_t)(p + 1) * kstep;
            A0 = *(const float4*)(np);
            A1 = *(const float4*)(np + 4);
        }

        f32x16 c0 = {0,0,0,0,0,0,0,0,0,0,0,0,0,0,0,0};
        f32x16 c1 = {0,0,0,0,0,0,0,0,0,0,0,0,0,0,0,0};
#pragma unroll
        for (int ks = 0; ks < 4; ++ks) {   // hi fragment feeds BOTH chains
            short8 kf = *(const short8*)&kbuf[cur][0][jrow][ks * 16 + kg * 8];
            c0 = mfma32(qh[ks], kf, c0);
            c1 = mfma32(ql[ks], kf, c1);
        }
#pragma unroll
        for (int ks = 0; ks < 4; ++ks) {   // lo fragments alternate chains
            short8 kf = *(const short8*)&kbuf[cur][1][jrow][ks * 16 + kg * 8];
            if (ks & 1) c1 = mfma32(qh[ks], kf, c1);
            else        c0 = mfma32(qh[ks], kf, c0);
        }

        const unsigned bb = (unsigned)(bstart + p);
#pragma unroll
        for (int r = 0; r < 16; ++r) {     // packed branchless top-2
            float v = c0[r] + c1[r];
            float vq = __uint_as_float((__float_as_uint(v) & 0xFFFFFF00u) | bb);
            m2[r]  = __builtin_amdgcn_fmed3f(vq, m1q[r], m2[r]);
            m1q[r] = fmaxf(m1q[r], vq);
        }

        if (p + 1 < nsteps) {              // convert + write next step late
            short8 h0, l0;
            cvt8f(A0, A1, h0, l0);
            const int nb = cur ^ 1;
            *(short8*)&kbuf[nb][0][r0][sub8] = h0;
            *(short8*)&kbuf[nb][1][r0][sub8] = l0;
            cur = nb;
        }
    }

#pragma unroll
    for (int r = 0; r < 16; ++r) {
        const int q = q0 + qg * 32 + 4 * kg + (r & 3) + 8 * (r >> 2);
        const size_t t = (((size_t)q * D_ + d) << 7) + j0 + jrow;
        const size_t pp = (size_t)half * NT_ + t;
        m1p[pp] = m1q[r]; m2p[pp] = m2[r];
    }
}

// ---------------------------------------------------------------------------
// Merge split-b partials -> final argmax byte + near-tie flag list.
// ---------------------------------------------------------------------------
__global__ void k_merge(const float* __restrict__ m1p, const float* __restrict__ m2p,
                        unsigned char* __restrict__ idx0b,
                        int* __restrict__ flag_cnt, int* __restrict__ flag_list)
{
    int t = blockIdx.x * 256 + threadIdx.x;
    if (t >= NT_) return;
    float m1 = -3e38f, m2 = -3e38f;
#pragma unroll
    for (int h = 0; h < SPLIT_; ++h) {
        float a    = m1p[(size_t)h * NT_ + t];
        float bsec = m2p[(size_t)h * NT_ + t];
        if (a > m1) { m2 = m1; m1 = a; }
        else if (a > m2) m2 = a;
        if (bsec > m2) m2 = bsec;
    }
    idx0b[t] = (unsigned char)(__float_as_uint(m1) & 0xFFu);
    if (m2 >= m1 - MARGIN_) {
        int pos = atomicAdd(flag_cnt, 1);
        if (pos < FLAG_CAP_) flag_list[pos] = t;
    }
}

// ---------------------------------------------------------------------------
// FixA: exact fp64-accum re-rank of flagged triples.
// ---------------------------------------------------------------------------
__global__ void k_fixA(const float* __restrict__ query, const float* __restrict__ key_db,
                       const int* __restrict__ flag_cnt, const int* __restrict__ flag_list,
                       unsigned char* __restrict__ idx0b, int* __restrict__ flag2_cnt,
                       int* __restrict__ flag2_list)
{
    int cnt = *flag_cnt;
    if (cnt > FLAG_CAP_) cnt = FLAG_CAP_;
    int gw   = (blockIdx.x * blockDim.x + threadIdx.x) >> 6;
    int lane = threadIdx.x & 63;
    int nw   = (gridDim.x * blockDim.x) >> 6;

    for (int w = gw; w < cnt; w += nw) {
        int t = flag_list[w];
        int j = t & 127, d = (t >> 7) & 7, qi = t >> 10;
        const float* qrow = query + ((size_t)qi * D_ + d) * F_;
        const float* kb = key_db + (size_t)d * DB_ * F_;

        double m1 = -1e300, m2 = -1e300; int i1 = 0;
#pragma unroll
        for (int i = 0; i < 4; ++i) {
            int b = lane * 4 + i;
            const float* krow = kb + ((size_t)b * NB_ + j) * F_;
            double a = 0.0;
            for (int k2 = 0; k2 < F_; ++k2) a += (double)qrow[k2] * (double)krow[k2];
            if (a > m1) { m2 = m1; m1 = a; i1 = b; }
            else if (a > m2) m2 = a;
        }
        for (int off = 32; off; off >>= 1) {
            double om1 = __shfl_xor(m1, off);
            double om2 = __shfl_xor(m2, off);
            int    oi  = __shfl_xor(i1, off);
            if (om1 > m1) { m2 = fmax(m1, om2); m1 = om1; i1 = oi; }
            else          { m2 = fmax(m2, om1); }
        }
        if (lane == 0) {
            idx0b[t] = (unsigned char)i1;
            if (m1 - m2 < MARGIN2_) {
                int pos = atomicAdd(flag2_cnt, 1);
                if (pos < 4096) flag2_list[pos] = t;
            }
        }
    }
}

// ---------------------------------------------------------------------------
// K2: gather, d PINNED TO XCD (blockIdx&7 = d). Each selected row is read
// ~4x (avg q-multiplicity per (d,j,b)); pinning makes rereads hit the same
// XCD's L2 instead of scattering across XCDs (all-L2-miss -> L3). Writes
// stay fully coalesced (within-d runs of 32KB). Non-temporal stores.
// ---------------------------------------------------------------------------
__global__ void k_gather(const float* __restrict__ key_db, const float* __restrict__ value_db,
                         const unsigned char* __restrict__ idx0b, f32x4* __restrict__ out)
{
    const int d    = blockIdx.x & 7;
    const int blk  = blockIdx.x >> 3;
    const int nblk = gridDim.x >> 3;
    const int perd = Q_ * NB_ * 16;        // float4 per dataset per half
    const float* kb = key_db + (size_t)d * DB_ * F_;
    const float* vb = value_db + (size_t)d * DB_ * F_;

    for (int u = blk * 256 + threadIdx.x; u < perd; u += nblk * 256) {
        int fc = u & 15;
        int jq = u >> 4;                   // q*128 + j
        int j  = jq & 127;
        int q  = jq >> 7;
        int t  = (q << 10) | (d << 7) | j; // (q*D + d)*128 + j
        int b  = idx0b[t];
        size_t rowoff = ((size_t)b * NB_ + j) * F_ + fc * 4;
        f32x4 kv = *(const f32x4*)(kb + rowoff);
        f32x4 vv = *(const f32x4*)(vb + rowoff);
        size_t e = (size_t)t * 16 + fc;
        __builtin_nontemporal_store(kv, &out[e]);
        __builtin_nontemporal_store(vv, &out[(size_t)NT_ * 16 + e]);
    }
}

// ---------------------------------------------------------------------------
// FixB: exact fp64 softmax for true near-tie triples.
// ---------------------------------------------------------------------------
__global__ void k_fixB(const float* __restrict__ query, const float* __restrict__ key_db,
                       const float* __restrict__ value_db, const int* __restrict__ flag_cnt,
                       const int* __restrict__ flag_list, float* __restrict__ out)
{
    int cnt = *flag_cnt;
    if (cnt > 4096) cnt = 4096;
    int gw   = (blockIdx.x * blockDim.x + threadIdx.x) >> 6;
    int lane = threadIdx.x & 63;
    int nw   = (gridDim.x * blockDim.x) >> 6;

    for (int w = gw; w < cnt; w += nw) {
        int t = flag_list[w];
        int j = t & 127, d = (t >> 7) & 7, qi = t >> 10;
        const float* qrow = query + ((size_t)qi * D_ + d) * F_;
        const float* kb = key_db + (size_t)d * DB_ * F_;
        const float* vb = value_db + (size_t)d * DB_ * F_;

        double sv[4];
#pragma unroll
        for (int i = 0; i < 4; ++i) {
            int b = lane * 4 + i;
            const float* krow = kb + ((size_t)b * NB_ + j) * F_;
            double a = 0.0;
            for (int k2 = 0; k2 < F_; ++k2) a += (double)qrow[k2] * (double)krow[k2];
            sv[i] = a;
        }
        double m = fmax(fmax(sv[0], sv[1]), fmax(sv[2], sv[3]));
        for (int off = 32; off; off >>= 1) m = fmax(m, __shfl_xor(m, off));
        double ev[4];
        double es = 0.0;
#pragma unroll
        for (int i = 0; i < 4; ++i) { ev[i] = exp((sv[i] - m) * 1e6); es += ev[i]; }
        for (int off = 32; off; off >>= 1) es += __shfl_xor(es, off);
        double inv = 1.0 / es;
#pragma unroll
        for (int i = 0; i < 4; ++i) ev[i] *= inv;

        double ak = 0.0, av = 0.0;
        for (int src = 0; src < 64; ++src) {
#pragma unroll
            for (int i = 0; i < 4; ++i) {
                double wv = __shfl(ev[i], src);
                if (wv > 1e-300) {
                    int b = src * 4 + i;
                    size_t o = ((size_t)b * NB_ + j) * F_ + lane;
                    ak += wv * (double)kb[o];
                    av += wv * (double)vb[o];
                }
            }
        }
        out[(size_t)t * F_ + lane] = (float)ak;
        out[(size_t)NT_ * F_ + (size_t)t * F_ + lane] = (float)av;
    }
}

// ---------------------------------------------------------------------------
extern "C" void kernel_launch(void* const* d_in, const int* in_sizes, int n_in,
                              void* d_out, int out_size, void* d_ws, size_t ws_size,
                              hipStream_t stream)
{
    const float* query    = (const float*)d_in[0];
    const float* key_db   = (const float*)d_in[1];
    const float* value_db = (const float*)d_in[2];
    float* out = (float*)d_out;

    unsigned char* idx0b = (unsigned char*)d_ws;
    int* flag_cnt   = (int*)((char*)d_ws + (size_t)NT_);
    int* flag2_cnt  = flag_cnt + 1;
    int* flag_list  = (int*)((char*)d_ws + (size_t)NT_ + 256);
    int* flag2_list = flag_list + FLAG_CAP_;

    float* m1p = (float*)d_out;                           // 32 MB
    float* m2p = m1p + (size_t)SPLIT_ * NT_;              // 32 MB

    (void)hipMemsetAsync(flag_cnt, 0, 8, stream);

    k_scan_mfma<<<1024, 512, 0, stream>>>(key_db, query, m1p, m2p);
    k_merge    <<<NT_ / 256, 256, 0, stream>>>(m1p, m2p, idx0b, flag_cnt, flag_list);
    k_fixA     <<<512,  256, 0, stream>>>(query, key_db, flag_cnt, flag_list,
                                          idx0b, flag2_cnt, flag2_list);
    k_gather   <<<4096, 256, 0, stream>>>(key_db, value_db, idx0b, (f32x4*)d_out);
    k_fixB     <<<256,  256, 0, stream>>>(query, key_db, value_db, flag2_cnt,
                                          flag2_list, out);
}

// Round 14
// 311.922 us; speedup vs baseline: 1.5257x; 1.0263x over previous
//
#include <hip/hip_runtime.h>

// Problem constants (fixed by the reference)
#define D_   8
#define Q_   1024
#define DB_  32768
#define F_   64
#define NB_  128      // num_buckets = num_neighbors
#define BS_  256      // bucket_size = DB/NB
#define NT_  (Q_*D_*NB_)   // 1,048,576 (q,d,j) triples
#define SPLIT_ 8      // split of the b-range across blocks
#define MARGIN_  6e-4f  // scan top-2 gap below which fixA re-ranks exactly
#define MARGIN2_ 2e-4   // fixA exact gap below which fixB does fp64 softmax
#define FLAG_CAP_ 262144

typedef __attribute__((ext_vector_type(16))) float    f32x16;
typedef __attribute__((ext_vector_type(4)))  float    f32x4;
typedef __attribute__((ext_vector_type(8)))  short    short8;
typedef __attribute__((ext_vector_type(8)))  __bf16   bf16x8;

static __device__ __forceinline__ f32x16 mfma32(short8 a, short8 b, f32x16 c) {
    return __builtin_amdgcn_mfma_f32_32x32x16_bf16(
        __builtin_bit_cast(bf16x8, a), __builtin_bit_cast(bf16x8, b), c, 0, 0, 0);
}

// ---------------------------------------------------------------------------
// In-register RNE split: x = hi + lo (both bf16, native casts ->
// v_cvt_pk_bf16_f32; verified on-device R9-R13).
// ---------------------------------------------------------------------------
static __device__ __forceinline__ void cvt8f(float4 a, float4 b,
                                             short8& kh, short8& kl) {
    float x0 = a.x, x1 = a.y, x2 = a.z, x3 = a.w;
    float x4 = b.x, x5 = b.y, x6 = b.z, x7 = b.w;
    bf16x8 h, l;
    h[0] = (__bf16)x0; l[0] = (__bf16)(x0 - (float)h[0]);
    h[1] = (__bf16)x1; l[1] = (__bf16)(x1 - (float)h[1]);
    h[2] = (__bf16)x2; l[2] = (__bf16)(x2 - (float)h[2]);
    h[3] = (__bf16)x3; l[3] = (__bf16)(x3 - (float)h[3]);
    h[4] = (__bf16)x4; l[4] = (__bf16)(x4 - (float)h[4]);
    h[5] = (__bf16)x5; l[5] = (__bf16)(x5 - (float)h[5]);
    h[6] = (__bf16)x6; l[6] = (__bf16)(x6 - (float)h[6]);
    h[7] = (__bf16)x7; l[7] = (__bf16)(x7 - (float)h[7]);
    kh = __builtin_bit_cast(short8, h);
    kl = __builtin_bit_cast(short8, l);
}

// ---------------------------------------------------------------------------
// K1: bf16 3-pass MFMA scan. Block = 128q x 64j, 8 waves (4qg x 2jg).
// TWO b-steps per barrier phase (16 phases, was 32): LDS widened to
// [buf][step][part][64][72] = 72KB (2 blocks/CU = 144KB <= 160). Halves
// the per-step vmcnt(0)+barrier drain events — the measured ~50% stall —
// and doubles the load-issue -> consume distance. Single-C accumulator
// (R12's c0/c1 split measured null; frees 16 VGPR to pay for the doubled
// staging registers). d = XCD id; top-2 packs b into m1's low 8 bits.
// ---------------------------------------------------------------------------
__global__ __launch_bounds__(512, 4) void k_scan_mfma(
    const float* __restrict__ key_db, const float* __restrict__ query,
    float* __restrict__ m1p, float* __restrict__ m2p)
{
    __shared__ short kbuf[2][2][2][64][72]; // [buf][step][part][row][col] = 72 KB
    const int tid  = threadIdx.x;
    const int d    = blockIdx.x & 7;        // dataset pinned to XCD
    const int idx  = blockIdx.x >> 3;       // 0..127 per d
    const int qi   = idx & 7;
    const int ji   = (idx >> 3) & 1;
    const int half = idx >> 4;              // 0..7
    const int q0 = qi * 128, j0 = ji * 64;
    const int wv = tid >> 6, lane = tid & 63;
    const int qg = wv >> 1, jg = wv & 1;
    const int lrow = lane & 31, kg = lane >> 5;

    short8 qh[4], ql[4];
    {
        const float* qr = query + ((size_t)(q0 + qg * 32 + lrow) * D_ + d) * F_ + kg * 8;
#pragma unroll
        for (int ks = 0; ks < 4; ++ks) {
            float4 A = *(const float4*)(qr + ks * 16);
            float4 B = *(const float4*)(qr + ks * 16 + 4);
            cvt8f(A, B, qh[ks], ql[ks]);
        }
    }

    float m1q[16], m2[16];
#pragma unroll
    for (int r = 0; r < 16; ++r) { m1q[r] = -3e38f; m2[r] = -3e38f; }

    const int nphases = (BS_ / SPLIT_) / 2;   // 16 phases, 2 steps each
    const int bstart = half * (BS_ / SPLIT_);
    const int r0 = tid >> 3, sub8 = (tid & 7) * 8;
    const float* sp = key_db + (size_t)d * DB_ * F_
                    + ((size_t)bstart * NB_ + j0) * F_
                    + (size_t)r0 * F_ + sub8;
    const size_t kstep = (size_t)NB_ * F_;

    { // prologue: stage steps 0,1 into buf 0
        float4 A0 = *(const float4*)(sp);
        float4 A1 = *(const float4*)(sp + 4);
        float4 B0 = *(const float4*)(sp + kstep);
        float4 B1 = *(const float4*)(sp + kstep + 4);
        short8 h0, l0, h1, l1;
        cvt8f(A0, A1, h0, l0);
        cvt8f(B0, B1, h1, l1);
        *(short8*)&kbuf[0][0][0][r0][sub8] = h0;
        *(short8*)&kbuf[0][0][1][r0][sub8] = l0;
        *(short8*)&kbuf[0][1][0][r0][sub8] = h1;
        *(short8*)&kbuf[0][1][1][r0][sub8] = l1;
    }

    const int jrow = jg * 32 + lrow;       // j index 0..63 within block
    int cur = 0;
    for (int p = 0; p < nphases; ++p) {
        __syncthreads();                   // buf[cur] ready; buf[cur^1] free
        float4 A0, A1, B0, B1;
        if (p + 1 < nphases) {             // issue next-phase loads (2 steps)
            const float* np = sp + (size_t)(2 * p + 2) * kstep;
            A0 = *(const float4*)(np);
            A1 = *(const float4*)(np + 4);
            B0 = *(const float4*)(np + kstep);
            B1 = *(const float4*)(np + kstep + 4);
        }

#pragma unroll
        for (int s = 0; s < 2; ++s) {
            f32x16 c = {0,0,0,0,0,0,0,0,0,0,0,0,0,0,0,0};
#pragma unroll
            for (int ks = 0; ks < 4; ++ks) {   // hi-part fragment used twice
                short8 kf = *(const short8*)&kbuf[cur][s][0][jrow][ks * 16 + kg * 8];
                c = mfma32(qh[ks], kf, c);
                c = mfma32(ql[ks], kf, c);
            }
#pragma unroll
            for (int ks = 0; ks < 4; ++ks) {   // lo-part fragment used once
                short8 kf = *(const short8*)&kbuf[cur][s][1][jrow][ks * 16 + kg * 8];
                c = mfma32(qh[ks], kf, c);
            }
            const unsigned bb = (unsigned)(bstart + 2 * p + s);
#pragma unroll
            for (int r = 0; r < 16; ++r) {     // packed branchless top-2
                float vq = __uint_as_float((__float_as_uint(c[r]) & 0xFFFFFF00u) | bb);
                m2[r]  = __builtin_amdgcn_fmed3f(vq, m1q[r], m2[r]);
                m1q[r] = fmaxf(m1q[r], vq);
            }
        }

        if (p + 1 < nphases) {             // convert + write next phase late
            short8 h0, l0, h1, l1;
            cvt8f(A0, A1, h0, l0);
            cvt8f(B0, B1, h1, l1);
            const int nb = cur ^ 1;
            *(short8*)&kbuf[nb][0][0][r0][sub8] = h0;
            *(short8*)&kbuf[nb][0][1][r0][sub8] = l0;
            *(short8*)&kbuf[nb][1][0][r0][sub8] = h1;
            *(short8*)&kbuf[nb][1][1][r0][sub8] = l1;
            cur = nb;
        }
    }

#pragma unroll
    for (int r = 0; r < 16; ++r) {
        const int q = q0 + qg * 32 + 4 * kg + (r & 3) + 8 * (r >> 2);
        const size_t t = (((size_t)q * D_ + d) << 7) + j0 + jrow;
        const size_t pp = (size_t)half * NT_ + t;
        m1p[pp] = m1q[r]; m2p[pp] = m2[r];
    }
}

// ---------------------------------------------------------------------------
// Merge split-b partials -> final argmax byte + near-tie flag list.
// ---------------------------------------------------------------------------
__global__ void k_merge(const float* __restrict__ m1p, const float* __restrict__ m2p,
                        unsigned char* __restrict__ idx0b,
                        int* __restrict__ flag_cnt, int* __restrict__ flag_list)
{
    int t = blockIdx.x * 256 + threadIdx.x;
    if (t >= NT_) return;
    float m1 = -3e38f, m2 = -3e38f;
#pragma unroll
    for (int h = 0; h < SPLIT_; ++h) {
        float a    = m1p[(size_t)h * NT_ + t];
        float bsec = m2p[(size_t)h * NT_ + t];
        if (a > m1) { m2 = m1; m1 = a; }
        else if (a > m2) m2 = a;
        if (bsec > m2) m2 = bsec;
    }
    idx0b[t] = (unsigned char)(__float_as_uint(m1) & 0xFFu);
    if (m2 >= m1 - MARGIN_) {
        int pos = atomicAdd(flag_cnt, 1);
        if (pos < FLAG_CAP_) flag_list[pos] = t;
    }
}

// ---------------------------------------------------------------------------
// FixA: exact fp64-accum re-rank of flagged triples.
// ---------------------------------------------------------------------------
__global__ void k_fixA(const float* __restrict__ query, const float* __restrict__ key_db,
                       const int* __restrict__ flag_cnt, const int* __restrict__ flag_list,
                       unsigned char* __restrict__ idx0b, int* __restrict__ flag2_cnt,
                       int* __restrict__ flag2_list)
{
    int cnt = *flag_cnt;
    if (cnt > FLAG_CAP_) cnt = FLAG_CAP_;
    int gw   = (blockIdx.x * blockDim.x + threadIdx.x) >> 6;
    int lane = threadIdx.x & 63;
    int nw   = (gridDim.x * blockDim.x) >> 6;

    for (int w = gw; w < cnt; w += nw) {
        int t = flag_list[w];
        int j = t & 127, d = (t >> 7) & 7, qi = t >> 10;
        const float* qrow = query + ((size_t)qi * D_ + d) * F_;
        const float* kb = key_db + (size_t)d * DB_ * F_;

        double m1 = -1e300, m2 = -1e300; int i1 = 0;
#pragma unroll
        for (int i = 0; i < 4; ++i) {
            int b = lane * 4 + i;
            const float* krow = kb + ((size_t)b * NB_ + j) * F_;
            double a = 0.0;
            for (int k2 = 0; k2 < F_; ++k2) a += (double)qrow[k2] * (double)krow[k2];
            if (a > m1) { m2 = m1; m1 = a; i1 = b; }
            else if (a > m2) m2 = a;
        }
        for (int off = 32; off; off >>= 1) {
            double om1 = __shfl_xor(m1, off);
            double om2 = __shfl_xor(m2, off);
            int    oi  = __shfl_xor(i1, off);
            if (om1 > m1) { m2 = fmax(m1, om2); m1 = om1; i1 = oi; }
            else          { m2 = fmax(m2, om1); }
        }
        if (lane == 0) {
            idx0b[t] = (unsigned char)i1;
            if (m1 - m2 < MARGIN2_) {
                int pos = atomicAdd(flag2_cnt, 1);
                if (pos < 4096) flag2_list[pos] = t;
            }
        }
    }
}

// ---------------------------------------------------------------------------
// K2: gather, d pinned to XCD. #pragma unroll 2 -> 4 independent row-loads
// in flight per thread. Non-temporal stores; writes are 32KB contiguous
// runs per (q,d); reads hit the d-slab warmed in this XCD's L2/L3.
// ---------------------------------------------------------------------------
__global__ void k_gather(const float* __restrict__ key_db, const float* __restrict__ value_db,
                         const unsigned char* __restrict__ idx0b, f32x4* __restrict__ out)
{
    const int d    = blockIdx.x & 7;
    const int blk  = blockIdx.x >> 3;
    const int nblk = gridDim.x >> 3;
    const int perd = Q_ * NB_ * 16;        // float4 per dataset per half
    const float* kb = key_db + (size_t)d * DB_ * F_;
    const float* vb = value_db + (size_t)d * DB_ * F_;

#pragma unroll 2
    for (int u = blk * 256 + threadIdx.x; u < perd; u += nblk * 256) {
        int fc = u & 15;
        int jq = u >> 4;                   // q*128 + j
        int j  = jq & 127;
        int q  = jq >> 7;
        int t  = (q << 10) | (d << 7) | j; // (q*D + d)*128 + j
        int b  = idx0b[t];
        size_t rowoff = ((size_t)b * NB_ + j) * F_ + fc * 4;
        f32x4 kv = *(const f32x4*)(kb + rowoff);
        f32x4 vv = *(const f32x4*)(vb + rowoff);
        size_t e = (size_t)t * 16 + fc;
        __builtin_nontemporal_store(kv, &out[e]);
        __builtin_nontemporal_store(vv, &out[(size_t)NT_ * 16 + e]);
    }
}

// ---------------------------------------------------------------------------
// FixB: exact fp64 softmax for true near-tie triples.
// ---------------------------------------------------------------------------
__global__ void k_fixB(const float* __restrict__ query, const float* __restrict__ key_db,
                       const float* __restrict__ value_db, const int* __restrict__ flag_cnt,
                       const int* __restrict__ flag_list, float* __restrict__ out)
{
    int cnt = *flag_cnt;
    if (cnt > 4096) cnt = 4096;
    int gw   = (blockIdx.x * blockDim.x + threadIdx.x) >> 6;
    int lane = threadIdx.x & 63;
    int nw   = (gridDim.x * blockDim.x) >> 6;

    for (int w = gw; w < cnt; w += nw) {
        int t = flag_list[w];
        int j = t & 127, d = (t >> 7) & 7, qi = t >> 10;
        const float* qrow = query + ((size_t)qi * D_ + d) * F_;
        const float* kb = key_db + (size_t)d * DB_ * F_;
        const float* vb = value_db + (size_t)d * DB_ * F_;

        double sv[4];
#pragma unroll
        for (int i = 0; i < 4; ++i) {
            int b = lane * 4 + i;
            const float* krow = kb + ((size_t)b * NB_ + j) * F_;
            double a = 0.0;
            for (int k2 = 0; k2 < F_; ++k2) a += (double)qrow[k2] * (double)krow[k2];
            sv[i] = a;
        }
        double m = fmax(fmax(sv[0], sv[1]), fmax(sv[2], sv[3]));
        for (int off = 32; off; off >>= 1) m = fmax(m, __shfl_xor(m, off));
        double ev[4];
        double es = 0.0;
#pragma unroll
        for (int i = 0; i < 4; ++i) { ev[i] = exp((sv[i] - m) * 1e6); es += ev[i]; }
        for (int off = 32; off; off >>= 1) es += __shfl_xor(es, off);
        double inv = 1.0 / es;
#pragma unroll
        for (int i = 0; i < 4; ++i) ev[i] *= inv;

        double ak = 0.0, av = 0.0;
        for (int src = 0; src < 64; ++src) {
#pragma unroll
            for (int i = 0; i < 4; ++i) {
                double wv = __shfl(ev[i], src);
                if (wv > 1e-300) {
                    int b = src * 4 + i;
                    size_t o = ((size_t)b * NB_ + j) * F_ + lane;
                    ak += wv * (double)kb[o];
                    av += wv * (double)vb[o];
                }
            }
        }
        out[(size_t)t * F_ + lane] = (float)ak;
        out[(size_t)NT_ * F_ + (size_t)t * F_ + lane] = (float)av;
    }
}

// ---------------------------------------------------------------------------
extern "C" void kernel_launch(void* const* d_in, const int* in_sizes, int n_in,
                              void* d_out, int out_size, void* d_ws, size_t ws_size,
                              hipStream_t stream)
{
    const float* query    = (const float*)d_in[0];
    const float* key_db   = (const float*)d_in[1];
    const float* value_db = (const float*)d_in[2];
    float* out = (float*)d_out;

    unsigned char* idx0b = (unsigned char*)d_ws;
    int* flag_cnt   = (int*)((char*)d_ws + (size_t)NT_);
    int* flag2_cnt  = flag_cnt + 1;
    int* flag_list  = (int*)((char*)d_ws + (size_t)NT_ + 256);
    int* flag2_list = flag_list + FLAG_CAP_;

    float* m1p = (float*)d_out;                           // 32 MB
    float* m2p = m1p + (size_t)SPLIT_ * NT_;              // 32 MB

    (void)hipMemsetAsync(flag_cnt, 0, 8, stream);

    k_scan_mfma<<<1024, 512, 0, stream>>>(key_db, query, m1p, m2p);
    k_merge    <<<NT_ / 256, 256, 0, stream>>>(m1p, m2p, idx0b, flag_cnt, flag_list);
    k_fixA     <<<512,  256, 0, stream>>>(query, key_db, flag_cnt, flag_list,
                                          idx0b, flag2_cnt, flag2_list);
    k_gather   <<<4096, 256, 0, stream>>>(key_db, value_db, idx0b, (f32x4*)d_out);
    k_fixB     <<<256,  256, 0, stream>>>(query, key_db, value_db, flag2_cnt,
                                          flag2_list, out);
}

// Round 15
// 305.225 us; speedup vs baseline: 1.5592x; 1.0219x over previous
//
#include <hip/hip_runtime.h>

// Problem constants (fixed by the reference)
#define D_   8
#define Q_   1024
#define DB_  32768
#define F_   64
#define NB_  128      // num_buckets = num_neighbors
#define BS_  256      // bucket_size = DB/NB
#define NT_  (Q_*D_*NB_)   // 1,048,576 (q,d,j) triples
#define SPLIT_ 4      // split of the b-range across blocks (512 blocks = one
                      // exact residency pass at 2 blocks/CU; halves partials)
#define MARGIN_  6e-4f  // scan top-2 gap below which fixA re-ranks exactly
#define MARGIN2_ 2e-4   // fixA exact gap below which fixB does fp64 softmax
#define FLAG_CAP_ 262144

typedef __attribute__((ext_vector_type(16))) float    f32x16;
typedef __attribute__((ext_vector_type(4)))  float    f32x4;
typedef __attribute__((ext_vector_type(8)))  short    short8;
typedef __attribute__((ext_vector_type(8)))  __bf16   bf16x8;

static __device__ __forceinline__ f32x16 mfma32(short8 a, short8 b, f32x16 c) {
    return __builtin_amdgcn_mfma_f32_32x32x16_bf16(
        __builtin_bit_cast(bf16x8, a), __builtin_bit_cast(bf16x8, b), c, 0, 0, 0);
}

// ---------------------------------------------------------------------------
// In-register RNE split: x = hi + lo (both bf16, native casts ->
// v_cvt_pk_bf16_f32; verified on-device R9-R14).
// ---------------------------------------------------------------------------
static __device__ __forceinline__ void cvt8f(float4 a, float4 b,
                                             short8& kh, short8& kl) {
    float x0 = a.x, x1 = a.y, x2 = a.z, x3 = a.w;
    float x4 = b.x, x5 = b.y, x6 = b.z, x7 = b.w;
    bf16x8 h, l;
    h[0] = (__bf16)x0; l[0] = (__bf16)(x0 - (float)h[0]);
    h[1] = (__bf16)x1; l[1] = (__bf16)(x1 - (float)h[1]);
    h[2] = (__bf16)x2; l[2] = (__bf16)(x2 - (float)h[2]);
    h[3] = (__bf16)x3; l[3] = (__bf16)(x3 - (float)h[3]);
    h[4] = (__bf16)x4; l[4] = (__bf16)(x4 - (float)h[4]);
    h[5] = (__bf16)x5; l[5] = (__bf16)(x5 - (float)h[5]);
    h[6] = (__bf16)x6; l[6] = (__bf16)(x6 - (float)h[6]);
    h[7] = (__bf16)x7; l[7] = (__bf16)(x7 - (float)h[7]);
    kh = __builtin_bit_cast(short8, h);
    kl = __builtin_bit_cast(short8, l);
}

// ---------------------------------------------------------------------------
// K1: bf16 3-pass MFMA scan (R14 structure, SPLIT=4). Block = 128q x 64j,
// 8 waves (4qg x 2jg). Two b-steps per barrier phase (32 phases of 64
// steps), 72KB double-buffered LDS, 2 blocks/CU. Grid 512 = one exact
// residency pass (no second scheduling wave / drain tail). Single-C
// accumulator; top-2 with b packed into m1's low 8 mantissa bits.
// d = XCD id for L2 slab locality.
// ---------------------------------------------------------------------------
__global__ __launch_bounds__(512, 4) void k_scan_mfma(
    const float* __restrict__ key_db, const float* __restrict__ query,
    float* __restrict__ m1p, float* __restrict__ m2p)
{
    __shared__ short kbuf[2][2][2][64][72]; // [buf][step][part][row][col] = 72 KB
    const int tid  = threadIdx.x;
    const int d    = blockIdx.x & 7;        // dataset pinned to XCD
    const int idx  = blockIdx.x >> 3;       // 0..63 per d
    const int qi   = idx & 7;
    const int ji   = (idx >> 3) & 1;
    const int half = idx >> 4;              // 0..3
    const int q0 = qi * 128, j0 = ji * 64;
    const int wv = tid >> 6, lane = tid & 63;
    const int qg = wv >> 1, jg = wv & 1;
    const int lrow = lane & 31, kg = lane >> 5;

    short8 qh[4], ql[4];
    {
        const float* qr = query + ((size_t)(q0 + qg * 32 + lrow) * D_ + d) * F_ + kg * 8;
#pragma unroll
        for (int ks = 0; ks < 4; ++ks) {
            float4 A = *(const float4*)(qr + ks * 16);
            float4 B = *(const float4*)(qr + ks * 16 + 4);
            cvt8f(A, B, qh[ks], ql[ks]);
        }
    }

    float m1q[16], m2[16];
#pragma unroll
    for (int r = 0; r < 16; ++r) { m1q[r] = -3e38f; m2[r] = -3e38f; }

    const int nphases = (BS_ / SPLIT_) / 2;   // 32 phases, 2 steps each
    const int bstart = half * (BS_ / SPLIT_);
    const int r0 = tid >> 3, sub8 = (tid & 7) * 8;
    const float* sp = key_db + (size_t)d * DB_ * F_
                    + ((size_t)bstart * NB_ + j0) * F_
                    + (size_t)r0 * F_ + sub8;
    const size_t kstep = (size_t)NB_ * F_;

    { // prologue: stage steps 0,1 into buf 0
        float4 A0 = *(const float4*)(sp);
        float4 A1 = *(const float4*)(sp + 4);
        float4 B0 = *(const float4*)(sp + kstep);
        float4 B1 = *(const float4*)(sp + kstep + 4);
        short8 h0, l0, h1, l1;
        cvt8f(A0, A1, h0, l0);
        cvt8f(B0, B1, h1, l1);
        *(short8*)&kbuf[0][0][0][r0][sub8] = h0;
        *(short8*)&kbuf[0][0][1][r0][sub8] = l0;
        *(short8*)&kbuf[0][1][0][r0][sub8] = h1;
        *(short8*)&kbuf[0][1][1][r0][sub8] = l1;
    }

    const int jrow = jg * 32 + lrow;       // j index 0..63 within block
    int cur = 0;
    for (int p = 0; p < nphases; ++p) {
        __syncthreads();                   // buf[cur] ready; buf[cur^1] free
        float4 A0, A1, B0, B1;
        if (p + 1 < nphases) {             // issue next-phase loads (2 steps)
            const float* np = sp + (size_t)(2 * p + 2) * kstep;
            A0 = *(const float4*)(np);
            A1 = *(const float4*)(np + 4);
            B0 = *(const float4*)(np + kstep);
            B1 = *(const float4*)(np + kstep + 4);
        }

#pragma unroll
        for (int s = 0; s < 2; ++s) {
            f32x16 c = {0,0,0,0,0,0,0,0,0,0,0,0,0,0,0,0};
#pragma unroll
            for (int ks = 0; ks < 4; ++ks) {   // hi-part fragment used twice
                short8 kf = *(const short8*)&kbuf[cur][s][0][jrow][ks * 16 + kg * 8];
                c = mfma32(qh[ks], kf, c);
                c = mfma32(ql[ks], kf, c);
            }
#pragma unroll
            for (int ks = 0; ks < 4; ++ks) {   // lo-part fragment used once
                short8 kf = *(const short8*)&kbuf[cur][s][1][jrow][ks * 16 + kg * 8];
                c = mfma32(qh[ks], kf, c);
            }
            const unsigned bb = (unsigned)(bstart + 2 * p + s);
#pragma unroll
            for (int r = 0; r < 16; ++r) {     // packed branchless top-2
                float vq = __uint_as_float((__float_as_uint(c[r]) & 0xFFFFFF00u) | bb);
                m2[r]  = __builtin_amdgcn_fmed3f(vq, m1q[r], m2[r]);
                m1q[r] = fmaxf(m1q[r], vq);
            }
        }

        if (p + 1 < nphases) {             // convert + write next phase late
            short8 h0, l0, h1, l1;
            cvt8f(A0, A1, h0, l0);
            cvt8f(B0, B1, h1, l1);
            const int nb = cur ^ 1;
            *(short8*)&kbuf[nb][0][0][r0][sub8] = h0;
            *(short8*)&kbuf[nb][0][1][r0][sub8] = l0;
            *(short8*)&kbuf[nb][1][0][r0][sub8] = h1;
            *(short8*)&kbuf[nb][1][1][r0][sub8] = l1;
            cur = nb;
        }
    }

#pragma unroll
    for (int r = 0; r < 16; ++r) {
        const int q = q0 + qg * 32 + 4 * kg + (r & 3) + 8 * (r >> 2);
        const size_t t = (((size_t)q * D_ + d) << 7) + j0 + jrow;
        const size_t pp = (size_t)half * NT_ + t;
        m1p[pp] = m1q[r]; m2p[pp] = m2[r];
    }
}

// ---------------------------------------------------------------------------
// Merge split-b partials (4 halves) -> argmax byte + near-tie flag list.
// ---------------------------------------------------------------------------
__global__ void k_merge(const float* __restrict__ m1p, const float* __restrict__ m2p,
                        unsigned char* __restrict__ idx0b,
                        int* __restrict__ flag_cnt, int* __restrict__ flag_list)
{
    int t = blockIdx.x * 256 + threadIdx.x;
    if (t >= NT_) return;
    float m1 = -3e38f, m2 = -3e38f;
#pragma unroll
    for (int h = 0; h < SPLIT_; ++h) {
        float a    = m1p[(size_t)h * NT_ + t];
        float bsec = m2p[(size_t)h * NT_ + t];
        if (a > m1) { m2 = m1; m1 = a; }
        else if (a > m2) m2 = a;
        if (bsec > m2) m2 = bsec;
    }
    idx0b[t] = (unsigned char)(__float_as_uint(m1) & 0xFFu);
    if (m2 >= m1 - MARGIN_) {
        int pos = atomicAdd(flag_cnt, 1);
        if (pos < FLAG_CAP_) flag_list[pos] = t;
    }
}

// ---------------------------------------------------------------------------
// FixA: exact fp64-accum re-rank of flagged triples.
// ---------------------------------------------------------------------------
__global__ void k_fixA(const float* __restrict__ query, const float* __restrict__ key_db,
                       const int* __restrict__ flag_cnt, const int* __restrict__ flag_list,
                       unsigned char* __restrict__ idx0b, int* __restrict__ flag2_cnt,
                       int* __restrict__ flag2_list)
{
    int cnt = *flag_cnt;
    if (cnt > FLAG_CAP_) cnt = FLAG_CAP_;
    int gw   = (blockIdx.x * blockDim.x + threadIdx.x) >> 6;
    int lane = threadIdx.x & 63;
    int nw   = (gridDim.x * blockDim.x) >> 6;

    for (int w = gw; w < cnt; w += nw) {
        int t = flag_list[w];
        int j = t & 127, d = (t >> 7) & 7, qi = t >> 10;
        const float* qrow = query + ((size_t)qi * D_ + d) * F_;
        const float* kb = key_db + (size_t)d * DB_ * F_;

        double m1 = -1e300, m2 = -1e300; int i1 = 0;
#pragma unroll
        for (int i = 0; i < 4; ++i) {
            int b = lane * 4 + i;
            const float* krow = kb + ((size_t)b * NB_ + j) * F_;
            double a = 0.0;
            for (int k2 = 0; k2 < F_; ++k2) a += (double)qrow[k2] * (double)krow[k2];
            if (a > m1) { m2 = m1; m1 = a; i1 = b; }
            else if (a > m2) m2 = a;
        }
        for (int off = 32; off; off >>= 1) {
            double om1 = __shfl_xor(m1, off);
            double om2 = __shfl_xor(m2, off);
            int    oi  = __shfl_xor(i1, off);
            if (om1 > m1) { m2 = fmax(m1, om2); m1 = om1; i1 = oi; }
            else          { m2 = fmax(m2, om1); }
        }
        if (lane == 0) {
            idx0b[t] = (unsigned char)i1;
            if (m1 - m2 < MARGIN2_) {
                int pos = atomicAdd(flag2_cnt, 1);
                if (pos < 4096) flag2_list[pos] = t;
            }
        }
    }
}

// ---------------------------------------------------------------------------
// K2: gather, d pinned to XCD, unroll 4 -> 8 independent row-loads in
// flight per thread. Non-temporal stores.
// ---------------------------------------------------------------------------
__global__ void k_gather(const float* __restrict__ key_db, const float* __restrict__ value_db,
                         const unsigned char* __restrict__ idx0b, f32x4* __restrict__ out)
{
    const int d    = blockIdx.x & 7;
    const int blk  = blockIdx.x >> 3;
    const int nblk = gridDim.x >> 3;
    const int perd = Q_ * NB_ * 16;        // float4 per dataset per half
    const float* kb = key_db + (size_t)d * DB_ * F_;
    const float* vb = value_db + (size_t)d * DB_ * F_;

#pragma unroll 4
    for (int u = blk * 256 + threadIdx.x; u < perd; u += nblk * 256) {
        int fc = u & 15;
        int jq = u >> 4;                   // q*128 + j
        int j  = jq & 127;
        int q  = jq >> 7;
        int t  = (q << 10) | (d << 7) | j; // (q*D + d)*128 + j
        int b  = idx0b[t];
        size_t rowoff = ((size_t)b * NB_ + j) * F_ + fc * 4;
        f32x4 kv = *(const f32x4*)(kb + rowoff);
        f32x4 vv = *(const f32x4*)(vb + rowoff);
        size_t e = (size_t)t * 16 + fc;
        __builtin_nontemporal_store(kv, &out[e]);
        __builtin_nontemporal_store(vv, &out[(size_t)NT_ * 16 + e]);
    }
}

// ---------------------------------------------------------------------------
// FixB: exact fp64 softmax for true near-tie triples.
// ---------------------------------------------------------------------------
__global__ void k_fixB(const float* __restrict__ query, const float* __restrict__ key_db,
                       const float* __restrict__ value_db, const int* __restrict__ flag_cnt,
                       const int* __restrict__ flag_list, float* __restrict__ out)
{
    int cnt = *flag_cnt;
    if (cnt > 4096) cnt = 4096;
    int gw   = (blockIdx.x * blockDim.x + threadIdx.x) >> 6;
    int lane = threadIdx.x & 63;
    int nw   = (gridDim.x * blockDim.x) >> 6;

    for (int w = gw; w < cnt; w += nw) {
        int t = flag_list[w];
        int j = t & 127, d = (t >> 7) & 7, qi = t >> 10;
        const float* qrow = query + ((size_t)qi * D_ + d) * F_;
        const float* kb = key_db + (size_t)d * DB_ * F_;
        const float* vb = value_db + (size_t)d * DB_ * F_;

        double sv[4];
#pragma unroll
        for (int i = 0; i < 4; ++i) {
            int b = lane * 4 + i;
            const float* krow = kb + ((size_t)b * NB_ + j) * F_;
            double a = 0.0;
            for (int k2 = 0; k2 < F_; ++k2) a += (double)qrow[k2] * (double)krow[k2];
            sv[i] = a;
        }
        double m = fmax(fmax(sv[0], sv[1]), fmax(sv[2], sv[3]));
        for (int off = 32; off; off >>= 1) m = fmax(m, __shfl_xor(m, off));
        double ev[4];
        double es = 0.0;
#pragma unroll
        for (int i = 0; i < 4; ++i) { ev[i] = exp((sv[i] - m) * 1e6); es += ev[i]; }
        for (int off = 32; off; off >>= 1) es += __shfl_xor(es, off);
        double inv = 1.0 / es;
#pragma unroll
        for (int i = 0; i < 4; ++i) ev[i] *= inv;

        double ak = 0.0, av = 0.0;
        for (int src = 0; src < 64; ++src) {
#pragma unroll
            for (int i = 0; i < 4; ++i) {
                double wv = __shfl(ev[i], src);
                if (wv > 1e-300) {
                    int b = src * 4 + i;
                    size_t o = ((size_t)b * NB_ + j) * F_ + lane;
                    ak += wv * (double)kb[o];
                    av += wv * (double)vb[o];
                }
            }
        }
        out[(size_t)t * F_ + lane] = (float)ak;
        out[(size_t)NT_ * F_ + (size_t)t * F_ + lane] = (float)av;
    }
}

// ---------------------------------------------------------------------------
extern "C" void kernel_launch(void* const* d_in, const int* in_sizes, int n_in,
                              void* d_out, int out_size, void* d_ws, size_t ws_size,
                              hipStream_t stream)
{
    const float* query    = (const float*)d_in[0];
    const float* key_db   = (const float*)d_in[1];
    const float* value_db = (const float*)d_in[2];
    float* out = (float*)d_out;

    unsigned char* idx0b = (unsigned char*)d_ws;
    int* flag_cnt   = (int*)((char*)d_ws + (size_t)NT_);
    int* flag2_cnt  = flag_cnt + 1;
    int* flag_list  = (int*)((char*)d_ws + (size_t)NT_ + 256);
    int* flag2_list = flag_list + FLAG_CAP_;

    float* m1p = (float*)d_out;                           // 16 MB
    float* m2p = m1p + (size_t)SPLIT_ * NT_;              // 16 MB

    (void)hipMemsetAsync(flag_cnt, 0, 8, stream);

    k_scan_mfma<<<512,  512, 0, stream>>>(key_db, query, m1p, m2p);
    k_merge    <<<NT_ / 256, 256, 0, stream>>>(m1p, m2p, idx0b, flag_cnt, flag_list);
    k_fixA     <<<512,  256, 0, stream>>>(query, key_db, flag_cnt, flag_list,
                                          idx0b, flag2_cnt, flag2_list);
    k_gather   <<<4096, 256, 0, stream>>>(key_db, value_db, idx0b, (f32x4*)d_out);
    k_fixB     <<<256,  256, 0, stream>>>(query, key_db, value_db, flag2_cnt,
                                          flag2_list, out);
}